// Round 3
// baseline (82.427 us; speedup 1.0000x reference)
//
#include <hip/hip_runtime.h>
#include <math.h>

// Problem constants (fixed by reference: inp (4,16,32,32) f32, weight (64,144) f32)
constexpr int F_IN   = 144;   // 16 ch * 9 taps
constexpr int F_OUT  = 64;
constexpr int H_IMG  = 32;
constexpr int W_IMG  = 32;
constexpr int NPIX   = 4 * H_IMG * W_IMG;  // 4096
constexpr int PPB    = 4;                  // pixels per block (1 wave each)
constexpr int NTHR   = PPB * 64;           // 256
#define MAX_SPIKE 100.0f

// ---------------------------------------------------------------------------
// ROUND-8: de-fuse. Round-2 counters showed fusion was a net LOSS:
// every one of 512 blocks recomputed all 9216 tanhf (~15% of kernel cycles
// of pure redundancy) + paid a block barrier. Restore the tiny quant kernel
// (validated round-6 source, byte-identical math) writing wqT to workspace.
// ---------------------------------------------------------------------------
__global__ __launch_bounds__(256) void quant_kernel(
    const float* __restrict__ w,
    float* __restrict__ wqT)   // (144,64) transposed
{
#pragma clang fp contract(off)
    __shared__ float wred[4];
    const int tid = threadIdx.x;

    float m = 0.f;
    {
        const float4* w4 = (const float4*)w;
        for (int i = tid; i < (F_OUT * F_IN) / 4; i += 256) {
            const float4 v = w4[i];
            m = fmaxf(m, fmaxf(fmaxf(fabsf(v.x), fabsf(v.y)),
                               fmaxf(fabsf(v.z), fabsf(v.w))));
        }
    }
    for (int s = 32; s > 0; s >>= 1)
        m = fmaxf(m, __shfl_xor(m, s, 64));
    if ((tid & 63) == 0) wred[tid >> 6] = m;
    __syncthreads();
    const float mw = fmaxf(fmaxf(wred[0], wred[1]), fmaxf(wred[2], wred[3]));
    const float alpha = tanhf(mw);

    const int i = blockIdx.x * 256 + tid;   // 36*256 = 9216 exactly
    const int o = i / F_IN;
    const int f = i - o * F_IN;
    const float t = tanhf(w[i]);
    float x = t / alpha;                       // f32 divide (mirrors np)
    x = fminf(fmaxf(x, -1.f), 1.f) * 127.f;    // clip then *qmax
    const float r = rintf(x);                  // round half-to-even
    wqT[f * F_OUT + o] = r * alpha / 127.f;    // mul then div (mirrors np)
}

// ---------------------------------------------------------------------------
// Spike scan v6: BARRIER-FREE.
//  * No LDS weight table: scan reads wq[f*64+lane] straight from global.
//    36 KB is L2-resident; lane-consecutive -> one coalesced 256B txn per
//    step; only ~40 reads/wave before the early exit. Removes the 36KB/block
//    staging, the vmcnt-drain barrier, and BOTH __syncthreads (kr/sv are
//    wave-private -> same-wave DS ordering suffices).
//  * PPB 8->4: 1024 blocks of 256 thr, finer load balance under the
//    data-dependent early-exit variance (round-2 occupancy was 30%).
//  * Sort loop batched 8x ds_read_b128 per iter (9 iters): doubles
//    outstanding LDS reads vs the old unroll-4 pair loop (~120cyc latency,
//    round-2 VALUBusy 45% = half the cycles were stall).
// Math identical op-for-op to validated rounds (indexing f*64+o unchanged).
// ---------------------------------------------------------------------------
__global__ __launch_bounds__(NTHR, 4) void spike_scan_kernel(
    const float* __restrict__ inp,   // (4,16,32,32)
    const float* __restrict__ wq,    // (144,64) quantized transposed
    float* __restrict__ out)         // (4,64,32,32)
{
#pragma clang fp contract(off)
    __shared__ __align__(16) unsigned long long kr[PPB][F_IN]; // 4.5 KB
    __shared__ float sv[PPB][F_IN + 1];                        // 2.3 KB

    const int tid  = threadIdx.x;
    const int lane = tid & 63;
    const int wv_i = tid >> 6;                   // wave id = pixel-in-block
    const int p    = blockIdx.x * PPB + wv_i;    // pixel id
    const int b    = p >> 10;
    const int l    = p & 1023;
    const int h    = l >> 5;
    const int wcol = l & 31;

    // ---- stage patch, build keys (feature f = c*9 + kh*3 + kw) ----
    float v0f, v1f, v2f;
    unsigned long long key0, key1, key2;
    {
        int idx[3] = { lane, lane + 64, lane + 128 };
        float vals[3];
        for (int m2 = 0; m2 < 3; ++m2) {
            const int i = idx[m2];
            float v = MAX_SPIKE;
            if (i < F_IN) {
                const int c  = i / 9;
                const int r  = i - c * 9;
                const int kh = r / 3;
                const int kw = r - kh * 3;
                const int hh = h + kh - 1;
                const int ww = wcol + kw - 1;
                float x = 0.f;
                if (hh >= 0 && hh < H_IMG && ww >= 0 && ww < W_IMG)
                    x = inp[((b * 16 + c) * H_IMG + hh) * W_IMG + ww];
                v = (x < 0.1f) ? MAX_SPIKE : x;
                kr[wv_i][i] = ((unsigned long long)__float_as_uint(v) << 8)
                              | (unsigned)i;
            }
            vals[m2] = v;
        }
        v0f = vals[0]; v1f = vals[1]; v2f = vals[2];
        key0 = ((unsigned long long)__float_as_uint(v0f) << 8) | (unsigned)idx[0];
        key1 = ((unsigned long long)__float_as_uint(v1f) << 8) | (unsigned)idx[1];
        key2 = ((unsigned long long)__float_as_uint(v2f) << 8) | (unsigned)idx[2];
        if (lane == 0) sv[wv_i][F_IN] = 1.0f;    // causality sentinel
    }
    // kr/sv wave-private: same-wave DS ordering is in-order -> no barrier.

    // ---- rank sort: batched 8x b128 reads/iter for deep LDS pipelining ----
    int r0 = 0, r1 = 0, r2 = 0;
    {
        const ulonglong2* ks2 = (const ulonglong2*)&kr[wv_i][0];
        for (int j = 0; j < F_IN / 2; j += 8) {   // 9 iterations
            const ulonglong2 ka = ks2[j + 0];
            const ulonglong2 kb = ks2[j + 1];
            const ulonglong2 kc = ks2[j + 2];
            const ulonglong2 kd = ks2[j + 3];
            const ulonglong2 ke = ks2[j + 4];
            const ulonglong2 kf = ks2[j + 5];
            const ulonglong2 kg = ks2[j + 6];
            const ulonglong2 kh2 = ks2[j + 7];
            r0 += (ka.x < key0) + (ka.y < key0) + (kb.x < key0) + (kb.y < key0)
                + (kc.x < key0) + (kc.y < key0) + (kd.x < key0) + (kd.y < key0)
                + (ke.x < key0) + (ke.y < key0) + (kf.x < key0) + (kf.y < key0)
                + (kg.x < key0) + (kg.y < key0) + (kh2.x < key0) + (kh2.y < key0);
            r1 += (ka.x < key1) + (ka.y < key1) + (kb.x < key1) + (kb.y < key1)
                + (kc.x < key1) + (kc.y < key1) + (kd.x < key1) + (kd.y < key1)
                + (ke.x < key1) + (ke.y < key1) + (kf.x < key1) + (kf.y < key1)
                + (kg.x < key1) + (kg.y < key1) + (kh2.x < key1) + (kh2.y < key1);
            r2 += (ka.x < key2) + (ka.y < key2) + (kb.x < key2) + (kb.y < key2)
                + (kc.x < key2) + (kc.y < key2) + (kd.x < key2) + (kd.y < key2)
                + (ke.x < key2) + (ke.y < key2) + (kf.x < key2) + (kf.y < key2)
                + (kg.x < key2) + (kg.y < key2) + (kh2.x < key2) + (kh2.y < key2);
        }
    }

    // ---- scatter sorted values + record-lo (wq row element offset f*64) ----
    {
        unsigned* krlo = (unsigned*)&kr[wv_i][0];   // little-endian: lo at +0
        sv[wv_i][r0] = v0f;  krlo[2 * r0] = (unsigned)lane << 6;
        sv[wv_i][r1] = v1f;  krlo[2 * r1] = (unsigned)(lane + 64) << 6;
        if (lane < F_IN - 128) {
            sv[wv_i][r2] = v2f;  krlo[2 * r2] = (unsigned)(lane + 128) << 6;
        }
    }

    // ---- record-hi = bits of next sorted value ----
    {
        unsigned* krhi = (unsigned*)&kr[wv_i][0];
        for (int k = lane; k < F_IN; k += 64)
            krhi[2 * k + 1] = __float_as_uint(sv[wv_i][k + 1]);
    }

    // ---- batched scan: first valid spike == min (wq read from global/L2) ----
    float s   = sv[wv_i][0];
    float ws  = 0.f;
    float iws = 0.f;
    float mn  = MAX_SPIKE;      // masked / never-valid lanes => exactly 100
    bool  done = false;
    const ulonglong2* rec2 = (const ulonglong2*)&kr[wv_i][0];
    for (int k0 = 0; k0 < F_IN; k0 += 8) {
        if (s >= MAX_SPIKE) break;            // sorted: rest contribute 100
        const ulonglong2 ra = rec2[(k0 >> 1) + 0];
        const ulonglong2 rb = rec2[(k0 >> 1) + 1];
        const ulonglong2 rc = rec2[(k0 >> 1) + 2];
        const ulonglong2 rd = rec2[(k0 >> 1) + 3];
        const unsigned long long r8[8] = { ra.x, ra.y, rb.x, rb.y,
                                           rc.x, rc.y, rd.x, rd.y };
        float su[8], nx[8], wsu[8], iwsu[8];
#pragma unroll
        for (int u = 0; u < 8; ++u) {
            su[u] = s;
            nx[u] = __uint_as_float((unsigned)(r8[u] >> 32));
            const float wvv = wq[(unsigned)r8[u] + lane];  // global, coalesced
            ws += wvv;
            const float prod = su[u] * wvv;   // separate rounding (no FMA)
            iws += prod;
            wsu[u]  = ws;
            iwsu[u] = iws;
            s = nx[u];
        }
        // wq >= 0 => ws monotone: if last ws of batch < 1 for all lanes, the
        // whole batch is masked (contributes exactly 100) -> skip div/compares.
        if (!__all(wsu[7] < 1.0f)) {
#pragma unroll
            for (int u = 0; u < 8; ++u) {
                const float d = fmaxf(wsu[u] - 1.0f, 1e-10f); // upper clamp never binds
                const float q = iwsu[u] / d;                  // IEEE f32 divide
                const bool valid = (wsu[u] >= 1.0f) & (q >= su[u]) & (q <= nx[u]);
                if (valid & !done) { mn = q; done = true; }
            }
            if (__all(done)) break;           // windows increase: first = min
        }
    }
    out[(b * F_OUT + lane) * 1024 + l] = mn;
}

extern "C" void kernel_launch(void* const* d_in, const int* in_sizes, int n_in,
                              void* d_out, int out_size, void* d_ws, size_t ws_size,
                              hipStream_t stream) {
    const float* inp = (const float*)d_in[0];   // 65536 elems
    const float* w   = (const float*)d_in[1];   // 9216 elems
    float* out = (float*)d_out;                 // 262144 elems
    float* wqT = (float*)d_ws;                  // 9216 floats scratch

    quant_kernel<<<36, 256, 0, stream>>>(w, wqT);
    spike_scan_kernel<<<NPIX / PPB, NTHR, 0, stream>>>(inp, wqT, out);
}